// Round 6
// baseline (119.876 us; speedup 1.0000x reference)
//
#include <hip/hip_runtime.h>
#include <hip/hip_fp16.h>

#define BATCH 16
#define H 512
#define W 512
#define BH 128
#define BW 128
#define HG 510   // interior rows (buffer rows 0..509 <-> pixel rows 1..510)
#define WG 510
#define PKW 512  // padded row stride of packed intermediate

// pack: (mag_bits & ~31) | o   -- o in [0,18) fits 5 bits; mag rel err ~3e-6
// o is chosen BEFORE truncation, so argmax decisions are bit-identical to ref.

// ---------------- Kernel 1: gradient + orientation, 4x4 px/thread ----------------
// At HBM floor (~11 us: 50 MB img read + 16.7 MB pk write) -- R5 evidence.
__global__ __launch_bounds__(256) void hog_grad(const float* __restrict__ img,
                                                unsigned int* __restrict__ pk)
{
    int gx = blockIdx.x * 64 + threadIdx.x;   // x-quad 0..127
    int qy = blockIdx.y * 4 + threadIdx.y;    // y-quad 0..127
    int b  = blockIdx.z;
    int x0 = gx * 4;                          // buffer col of px 0 (aligned)
    int y0 = qy * 4;                          // buffer row of output row 0
    bool edge = (x0 < 508);

    const float* im = img + (size_t)b * 3 * H * W;

    float bv[16], bx[16], by[16];
#pragma unroll
    for (int i = 0; i < 16; i++) { bv[i] = -1.f; bx[i] = 0.f; by[i] = 0.f; }

#pragma unroll
    for (int c = 0; c < 3; c++) {
        const float* base = im + (size_t)c * H * W;
        float Wr[6][6];
#pragma unroll
        for (int j = 0; j < 6; j++) {
            int pr = y0 + j; if (pr > 511) pr = 511;   // clamped rows feed only masked outputs
            const float* rowp = base + (size_t)pr * W + x0;
            float4 a = *(const float4*)rowp;
            Wr[j][0] = a.x; Wr[j][1] = a.y; Wr[j][2] = a.z; Wr[j][3] = a.w;
            if (j >= 1 && j <= 4) {
                if (edge || pr < 511) {
                    float2 f = *(const float2*)(rowp + 4);
                    Wr[j][4] = f.x; Wr[j][5] = f.y;
                } else { Wr[j][4] = 0.f; Wr[j][5] = 0.f; }
            } else {
                Wr[j][4] = edge ? rowp[4] : 0.0f;
                Wr[j][5] = 0.f;
            }
        }
#pragma unroll
        for (int r = 0; r < 4; r++) {
#pragma unroll
            for (int i = 0; i < 4; i++) {
                float dx = __fsub_rn(Wr[r + 1][i + 2], Wr[r + 1][i]);
                float dy = __fsub_rn(Wr[r + 2][i + 1], Wr[r][i + 1]);
                float v = __fadd_rn(__fmul_rn(dx, dx), __fmul_rn(dy, dy));
                int k = r * 4 + i;
                if (v > bv[k]) { bv[k] = v; bx[k] = dx; by[k] = dy; }
            }
        }
    }

    const float uu[9] = {1.0f, 0.9397f, 0.766f, 0.5f, 0.1736f, -0.1736f, -0.5f, -0.766f, -0.9397f};
    const float vv[9] = {0.0f, 0.342f, 0.6428f, 0.866f, 0.9848f, 0.9848f, 0.866f, 0.6428f, 0.342f};

#pragma unroll
    for (int r = 0; r < 4; r++) {
        int y = y0 + r;
        if (y >= HG) break;
        unsigned int pkv[4];
#pragma unroll
        for (int i = 0; i < 4; i++) {
            int k = r * 4 + i;
            float mg = __fsqrt_rn(bv[k]);
            float d[9];
#pragma unroll
            for (int o = 0; o < 9; o++)
                d[o] = __fadd_rn(__fmul_rn(uu[o], bx[k]), __fmul_rn(vv[o], by[k]));
            float best = -1e30f; int bo = 0;
#pragma unroll
            for (int o = 0; o < 9; o++) { if (d[o] > best) { best = d[o]; bo = o; } }
#pragma unroll
            for (int o = 0; o < 9; o++) { float nd = -d[o]; if (nd > best) { best = nd; bo = o + 9; } }
            unsigned int v = (__float_as_uint(mg) & 0xFFFFFFE0u) | (unsigned int)bo;
            pkv[i] = (x0 + i < WG) ? v : 0u;
        }
        uint4 o4 = make_uint4(pkv[0], pkv[1], pkv[2], pkv[3]);
        *(uint4*)(pk + ((size_t)b * HG + y) * PKW + x0) = o4;
    }
}

// ---------------- Kernel 2: per-cell 8x8 bilinear gather -> hist(fp16x2) + norm ----------------
// fp16-packed LDS accumulation (bins o,o+9 in one dword, v_pk_add_f16 RMW):
// DS ops 200->164/thread, LDS 36->18 KB -> 8 blocks/CU = 32 waves/CU (2x occ).
// Two alternating buffers split the compiler-serialized RMW chain (R4).
// NO LDS fp32 atomics (~5x slower, R3). Bank addr o9*256+t -> conflict-free.
__global__ __launch_bounds__(256) void hog_hist(const unsigned int* __restrict__ pk,
                                                __half2* __restrict__ hist,
                                                float* __restrict__ nrm)
{
    __shared__ __half2 hl0[9 * 256];
    __shared__ __half2 hl1[9 * 256];
    int cx = threadIdx.x;                   // 0..127
    int cy = blockIdx.y * 2 + threadIdx.y;  // 0..127
    int b = blockIdx.z;
    int t = threadIdx.y * 128 + cx;

    const __half2 z2 = __halves2half2(__ushort_as_half(0), __ushort_as_half(0));
#pragma unroll
    for (int o = 0; o < 9; o++) { hl0[o * 256 + t] = z2; hl1[o * 256 + t] = z2; }

    const float wt[8] = {0.125f, 0.375f, 0.625f, 0.875f, 0.875f, 0.625f, 0.375f, 0.125f};
    const float wl[4] = {0.0f, 0.125f, 0.375f, 0.625f};   // pixels 4c-4..4c-1
    const float wm[4] = {0.875f, 0.875f, 0.625f, 0.375f}; // pixels 4c..4c+3

    const unsigned int* pb = pk + (size_t)b * HG * PKW;
    int ry0 = 4 * cy - 3;
    int xb = 4 * cx;

    // weight*mag computed in fp32, converted once; accumulation in fp16 pairs.
#define ACC(B, P, WW) { unsigned _p = (P); unsigned _o = _p & 31u;                         \
        __half _hv = __float2half((WW) * __uint_as_float(_p & 0xFFFFFFE0u));               \
        bool _lo = _o < 9u; unsigned _o9 = _lo ? _o : _o - 9u;                             \
        __half2 _ad = _lo ? __halves2half2(_hv, __ushort_as_half(0))                       \
                          : __halves2half2(__ushort_as_half(0), _hv);                      \
        B[_o9 * 256 + t] = __hadd2(B[_o9 * 256 + t], _ad); }

#pragma unroll
    for (int ky = 0; ky < 8; ky++) {
        int ry = ry0 + ky;
        if ((unsigned)ry >= (unsigned)HG) continue;  // wave-uniform
        float wy = wt[ky];
        const unsigned int* row = pb + (size_t)ry * PKW;
        if (cx > 0) {
            uint4 L = *(const uint4*)(row + xb - 4);
            ACC(hl0, L.y, wy * wl[1]);
            ACC(hl1, L.z, wy * wl[2]);
            ACC(hl0, L.w, wy * wl[3]);
        }
        uint4 M = *(const uint4*)(row + xb);
        ACC(hl1, M.x, wy * wm[0]);
        ACC(hl0, M.y, wy * wm[1]);
        if (cx < 127) {
            ACC(hl1, M.z, wy * wm[2]);
            ACC(hl0, M.w, wy * wm[3]);
            ACC(hl1, row[xb + 4], wy * 0.125f);
        }
    }
#undef ACC

    float s = 0.0f;
#pragma unroll
    for (int o = 0; o < 9; o++) {
        __half2 hh = __hadd2(hl0[o * 256 + t], hl1[o * 256 + t]);
        hist[(((size_t)b * 9 + o) * BH + cy) * BW + cx] = hh;
        float2 f = __half22float2(hh);
        float ss = f.x + f.y;
        s += ss * ss;
    }
    nrm[((size_t)b * BH + cy) * BW + cx] = s;
}

// ---------------- Kernel 3: normalization + features, 4 cells/thread ----------------
// float4 out stores (31 store instrs vs 124), b128 hist loads, amortized nrm loads.
__global__ __launch_bounds__(256) void hog_feat(const __half2* __restrict__ hist,
                                                const float* __restrict__ nrm,
                                                float* __restrict__ out)
{
    int tx = threadIdx.x;                   // 0..31 (x-quad)
    int oy = blockIdx.y * 8 + threadIdx.y;  // 0..127
    int b  = blockIdx.z;
    int cx0 = tx * 4;

    if (oy == 0 || oy == BH - 1) {
        float4 z4 = make_float4(0.f, 0.f, 0.f, 0.f);
#pragma unroll
        for (int c = 0; c < 31; c++)
            *(float4*)(out + (((size_t)b * 31 + c) * BH + oy) * BW + cx0) = z4;
        return;
    }

    // rsqrt factors per cell. Stray +/-1 col reads at the global ends land
    // inside d_ws (hist region / past-nrm scratch) -> in-bounds garbage, only
    // feeds masked border cells; fminf(NaN,0.2)=0.2 keeps it finite pre-mask.
    float v1[4], v2[4], v3[4], v4[4];
    {
        const float* nb = nrm + (size_t)b * BH * BW;
        float nn[3][6];
#pragma unroll
        for (int r = 0; r < 3; r++) {
            const float* rp = nb + (size_t)(oy - 1 + r) * BW + cx0;
#pragma unroll
            for (int j = 0; j < 6; j++) nn[r][j] = rp[j - 1];
        }
#pragma unroll
        for (int i = 0; i < 4; i++) {
            float T11 = nn[1][i+1] + nn[2][i+1] + nn[1][i+2] + nn[2][i+2];
            float T01 = nn[0][i+1] + nn[1][i+1] + nn[0][i+2] + nn[1][i+2];
            float T10 = nn[1][i]   + nn[2][i]   + nn[1][i+1] + nn[2][i+1];
            float T00 = nn[0][i]   + nn[1][i]   + nn[0][i+1] + nn[1][i+1];
            v1[i] = 1.0f / __fsqrt_rn(T11 + 1e-4f);
            v2[i] = 1.0f / __fsqrt_rn(T01 + 1e-4f);
            v3[i] = 1.0f / __fsqrt_rn(T10 + 1e-4f);
            v4[i] = 1.0f / __fsqrt_rn(T00 + 1e-4f);
        }
    }

    float h[4][18];
#pragma unroll
    for (int o = 0; o < 9; o++) {
        uint4 q = *(const uint4*)(hist + (((size_t)b * 9 + o) * BH + oy) * BW + cx0);
        unsigned vs[4] = {q.x, q.y, q.z, q.w};
#pragma unroll
        for (int i = 0; i < 4; i++) {
            float2 f = __half22float2(*(__half2*)&vs[i]);
            h[i][o] = f.x; h[i][o + 9] = f.y;
        }
    }

    bool msk[4];
#pragma unroll
    for (int i = 0; i < 4; i++) { int cxi = cx0 + i; msk[i] = (cxi >= 1 && cxi <= 126); }

    float t1[4] = {0,0,0,0}, t2[4] = {0,0,0,0}, t3[4] = {0,0,0,0}, t4[4] = {0,0,0,0};
    float* ob = out + ((size_t)b * 31) * BH * BW + (size_t)oy * BW + cx0;

#pragma unroll
    for (int o = 0; o < 18; o++) {
        float st[4];
#pragma unroll
        for (int i = 0; i < 4; i++) {
            float s = h[i][o];
            float a1 = fminf(s * v1[i], 0.2f);
            float a2 = fminf(s * v2[i], 0.2f);
            float a3 = fminf(s * v3[i], 0.2f);
            float a4 = fminf(s * v4[i], 0.2f);
            t1[i] += a1; t2[i] += a2; t3[i] += a3; t4[i] += a4;
            st[i] = msk[i] ? 0.5f * (a1 + a2 + a3 + a4) : 0.f;
        }
        *(float4*)(ob + (size_t)o * BH * BW) = make_float4(st[0], st[1], st[2], st[3]);
    }
#pragma unroll
    for (int o = 0; o < 9; o++) {
        float st[4];
#pragma unroll
        for (int i = 0; i < 4; i++) {
            float ss = h[i][o] + h[i][o + 9];
            float a1 = fminf(ss * v1[i], 0.2f);
            float a2 = fminf(ss * v2[i], 0.2f);
            float a3 = fminf(ss * v3[i], 0.2f);
            float a4 = fminf(ss * v4[i], 0.2f);
            st[i] = msk[i] ? 0.5f * (a1 + a2 + a3 + a4) : 0.f;
        }
        *(float4*)(ob + (size_t)(18 + o) * BH * BW) = make_float4(st[0], st[1], st[2], st[3]);
    }
    {
        float s1[4], s2[4], s3[4], s4[4];
#pragma unroll
        for (int i = 0; i < 4; i++) {
            s1[i] = msk[i] ? 0.2357f * t1[i] : 0.f;
            s2[i] = msk[i] ? 0.2357f * t2[i] : 0.f;
            s3[i] = msk[i] ? 0.2357f * t3[i] : 0.f;
            s4[i] = msk[i] ? 0.2357f * t4[i] : 0.f;
        }
        *(float4*)(ob + (size_t)27 * BH * BW) = make_float4(s1[0], s1[1], s1[2], s1[3]);
        *(float4*)(ob + (size_t)28 * BH * BW) = make_float4(s2[0], s2[1], s2[2], s2[3]);
        *(float4*)(ob + (size_t)29 * BH * BW) = make_float4(s3[0], s3[1], s3[2], s3[3]);
        *(float4*)(ob + (size_t)30 * BH * BW) = make_float4(s4[0], s4[1], s4[2], s4[3]);
    }
}

extern "C" void kernel_launch(void* const* d_in, const int* in_sizes, int n_in,
                              void* d_out, int out_size, void* d_ws, size_t ws_size,
                              hipStream_t stream)
{
    const float* img = (const float*)d_in[0];
    float* out = (float*)d_out;
    char* ws = (char*)d_ws;

    // workspace layout (256-aligned offsets):
    //   pk   : 16*510*512*4 = 16,711,680  @ 0
    //   hist : 16*9*128*128*4 = 9,437,184 @ 16,715,776  (half2-packed bins o|o+9)
    //   nrm  : 16*128*128*4 = 1,048,576  @ 26,152,960   (end 27,201,536)
    unsigned int* pk = (unsigned int*)ws;
    __half2* hist    = (__half2*)(ws + 16715776);
    float* nrm       = (float*)(ws + 26152960);

    dim3 b1(64, 4, 1), g1(2, 32, BATCH);
    hog_grad<<<g1, b1, 0, stream>>>(img, pk);

    dim3 b2(128, 2, 1), g2(1, BH / 2, BATCH);
    hog_hist<<<g2, b2, 0, stream>>>(pk, hist, nrm);

    dim3 b3(32, 8, 1), g3(1, BH / 8, BATCH);
    hog_feat<<<g3, b3, 0, stream>>>(hist, nrm, out);
}

// Round 7
// 116.101 us; speedup vs baseline: 1.0325x; 1.0325x over previous
//
#include <hip/hip_runtime.h>
#include <hip/hip_fp16.h>

#define BATCH 16
#define H 512
#define W 512
#define BH 128
#define BW 128
#define HG 510   // interior rows (buffer rows 0..509 <-> pixel rows 1..510)
#define WG 510
#define PKW 512  // padded row stride of packed intermediate

// pack: (mag_bits & ~31) | o   -- o in [0,18) fits 5 bits; mag rel err ~3e-6
// o is chosen BEFORE truncation, so argmax decisions are bit-identical to ref.

// ---------------- Kernel 1: gradient + orientation, 4x4 px/thread ----------------
// At HBM floor (~11 us: 50 MB img read + 16.7 MB pk write) -- R5 evidence.
__global__ __launch_bounds__(256) void hog_grad(const float* __restrict__ img,
                                                unsigned int* __restrict__ pk)
{
    int gx = blockIdx.x * 64 + threadIdx.x;   // x-quad 0..127
    int qy = blockIdx.y * 4 + threadIdx.y;    // y-quad 0..127
    int b  = blockIdx.z;
    int x0 = gx * 4;                          // buffer col of px 0 (aligned)
    int y0 = qy * 4;                          // buffer row of output row 0
    bool edge = (x0 < 508);

    const float* im = img + (size_t)b * 3 * H * W;

    float bv[16], bx[16], by[16];
#pragma unroll
    for (int i = 0; i < 16; i++) { bv[i] = -1.f; bx[i] = 0.f; by[i] = 0.f; }

#pragma unroll
    for (int c = 0; c < 3; c++) {
        const float* base = im + (size_t)c * H * W;
        float Wr[6][6];
#pragma unroll
        for (int j = 0; j < 6; j++) {
            int pr = y0 + j; if (pr > 511) pr = 511;   // clamped rows feed only masked outputs
            const float* rowp = base + (size_t)pr * W + x0;
            float4 a = *(const float4*)rowp;
            Wr[j][0] = a.x; Wr[j][1] = a.y; Wr[j][2] = a.z; Wr[j][3] = a.w;
            if (j >= 1 && j <= 4) {
                if (edge || pr < 511) {
                    float2 f = *(const float2*)(rowp + 4);
                    Wr[j][4] = f.x; Wr[j][5] = f.y;
                } else { Wr[j][4] = 0.f; Wr[j][5] = 0.f; }
            } else {
                Wr[j][4] = edge ? rowp[4] : 0.0f;
                Wr[j][5] = 0.f;
            }
        }
#pragma unroll
        for (int r = 0; r < 4; r++) {
#pragma unroll
            for (int i = 0; i < 4; i++) {
                float dx = __fsub_rn(Wr[r + 1][i + 2], Wr[r + 1][i]);
                float dy = __fsub_rn(Wr[r + 2][i + 1], Wr[r][i + 1]);
                float v = __fadd_rn(__fmul_rn(dx, dx), __fmul_rn(dy, dy));
                int k = r * 4 + i;
                if (v > bv[k]) { bv[k] = v; bx[k] = dx; by[k] = dy; }
            }
        }
    }

    const float uu[9] = {1.0f, 0.9397f, 0.766f, 0.5f, 0.1736f, -0.1736f, -0.5f, -0.766f, -0.9397f};
    const float vv[9] = {0.0f, 0.342f, 0.6428f, 0.866f, 0.9848f, 0.9848f, 0.866f, 0.6428f, 0.342f};

#pragma unroll
    for (int r = 0; r < 4; r++) {
        int y = y0 + r;
        if (y >= HG) break;
        unsigned int pkv[4];
#pragma unroll
        for (int i = 0; i < 4; i++) {
            int k = r * 4 + i;
            float mg = __fsqrt_rn(bv[k]);
            float d[9];
#pragma unroll
            for (int o = 0; o < 9; o++)
                d[o] = __fadd_rn(__fmul_rn(uu[o], bx[k]), __fmul_rn(vv[o], by[k]));
            float best = -1e30f; int bo = 0;
#pragma unroll
            for (int o = 0; o < 9; o++) { if (d[o] > best) { best = d[o]; bo = o; } }
#pragma unroll
            for (int o = 0; o < 9; o++) { float nd = -d[o]; if (nd > best) { best = nd; bo = o + 9; } }
            unsigned int v = (__float_as_uint(mg) & 0xFFFFFFE0u) | (unsigned int)bo;
            pkv[i] = (x0 + i < WG) ? v : 0u;
        }
        uint4 o4 = make_uint4(pkv[0], pkv[1], pkv[2], pkv[3]);
        *(uint4*)(pk + ((size_t)b * HG + y) * PKW + x0) = o4;
    }
}

// ---------------- Kernel 2: per-cell 8x8 bilinear gather -> hist(fp16x2) + norm ----------------
// R7: ALL 24 row-loads hoisted & unconditional (clamped addresses, zero weights
// for invalid rows/cols -- adding +0.0 to a non-negative bin is an exact no-op).
// Kills the 8 serialized global round-trips the per-row guards forced (R2-R6
// all ~17 us regardless of DS scheme => latency-bound, not DS-bound).
// fp16-packed accumulation (R6), two alternating buffers (R4), no LDS fp32
// atomics (~5x slower, R3).
__global__ __launch_bounds__(256) void hog_hist(const unsigned int* __restrict__ pk,
                                                __half2* __restrict__ hist,
                                                float* __restrict__ nrm)
{
    __shared__ __half2 hl0[9 * 256];
    __shared__ __half2 hl1[9 * 256];
    int cx = threadIdx.x;                   // 0..127
    int cy = blockIdx.y * 2 + threadIdx.y;  // 0..127
    int b = blockIdx.z;
    int t = threadIdx.y * 128 + cx;

    const float wt[8] = {0.125f, 0.375f, 0.625f, 0.875f, 0.875f, 0.625f, 0.375f, 0.125f};
    const float wl[4] = {0.0f, 0.125f, 0.375f, 0.625f};   // pixels 4c-4..4c-1
    const float wm[4] = {0.875f, 0.875f, 0.625f, 0.375f}; // pixels 4c..4c+3

    const unsigned int* pb = pk + (size_t)b * HG * PKW;
    int ry0 = 4 * cy - 3;
    int xb = 4 * cx;
    int xL = (cx > 0) ? xb - 4 : xb;        // clamped; weight-zeroed below
    int xR = (cx < 127) ? xb + 4 : xb;      // clamped; weight-zeroed below
    float wLm = (cx > 0) ? 1.0f : 0.0f;
    float wRm = (cx < 127) ? 1.0f : 0.0f;
    // NOTE: M.z/M.w at cx==127 read pk cols 510/511 which k1 zero-padded ->
    // contribution 0 with full weight; no mask needed.

    // ---- hoisted loads: issue everything, wait once ----
    uint4 Lv[8], Mv[8]; unsigned Xv[8]; float wyv[8];
#pragma unroll
    for (int ky = 0; ky < 8; ky++) {
        int ry = ry0 + ky;
        bool ok = (unsigned)ry < (unsigned)HG;
        int ryc = ok ? ry : (ry < 0 ? 0 : HG - 1);
        const unsigned int* row = pb + (size_t)ryc * PKW;
        Lv[ky] = *(const uint4*)(row + xL);
        Mv[ky] = *(const uint4*)(row + xb);
        Xv[ky] = row[xR];
        wyv[ky] = ok ? wt[ky] : 0.0f;
    }

    const __half2 z2 = __halves2half2(__ushort_as_half(0), __ushort_as_half(0));
#pragma unroll
    for (int o = 0; o < 9; o++) { hl0[o * 256 + t] = z2; hl1[o * 256 + t] = z2; }
    // per-thread private columns: no barrier; bank = t%32 -> 2-way (free)

#define ACC(B, P, WW) { unsigned _p = (P); unsigned _o = _p & 31u;                         \
        __half _hv = __float2half((WW) * __uint_as_float(_p & 0xFFFFFFE0u));               \
        bool _lo = _o < 9u; unsigned _o9 = _lo ? _o : _o - 9u;                             \
        __half2 _ad = _lo ? __halves2half2(_hv, __ushort_as_half(0))                       \
                          : __halves2half2(__ushort_as_half(0), _hv);                      \
        B[_o9 * 256 + t] = __hadd2(B[_o9 * 256 + t], _ad); }

#pragma unroll
    for (int ky = 0; ky < 8; ky++) {
        float wy = wyv[ky];
        uint4 L = Lv[ky], M = Mv[ky];
        ACC(hl0, L.y, (wy * wl[1]) * wLm);
        ACC(hl1, L.z, (wy * wl[2]) * wLm);
        ACC(hl0, L.w, (wy * wl[3]) * wLm);
        ACC(hl1, M.x, wy * wm[0]);
        ACC(hl0, M.y, wy * wm[1]);
        ACC(hl1, M.z, wy * wm[2]);
        ACC(hl0, M.w, wy * wm[3]);
        ACC(hl1, Xv[ky], (wy * 0.125f) * wRm);
    }
#undef ACC

    float s = 0.0f;
#pragma unroll
    for (int o = 0; o < 9; o++) {
        __half2 hh = __hadd2(hl0[o * 256 + t], hl1[o * 256 + t]);
        hist[(((size_t)b * 9 + o) * BH + cy) * BW + cx] = hh;
        float2 f = __half22float2(hh);
        float ss = f.x + f.y;
        s += ss * ss;
    }
    nrm[((size_t)b * BH + cy) * BW + cx] = s;
}

// ---------------- Kernel 3: normalization + features, 4 cells/thread ----------------
__global__ __launch_bounds__(256) void hog_feat(const __half2* __restrict__ hist,
                                                const float* __restrict__ nrm,
                                                float* __restrict__ out)
{
    int tx = threadIdx.x;                   // 0..31 (x-quad)
    int oy = blockIdx.y * 8 + threadIdx.y;  // 0..127
    int b  = blockIdx.z;
    int cx0 = tx * 4;

    if (oy == 0 || oy == BH - 1) {
        float4 z4 = make_float4(0.f, 0.f, 0.f, 0.f);
#pragma unroll
        for (int c = 0; c < 31; c++)
            *(float4*)(out + (((size_t)b * 31 + c) * BH + oy) * BW + cx0) = z4;
        return;
    }

    float v1[4], v2[4], v3[4], v4[4];
    {
        const float* nb = nrm + (size_t)b * BH * BW;
        float nn[3][6];
#pragma unroll
        for (int r = 0; r < 3; r++) {
            const float* rp = nb + (size_t)(oy - 1 + r) * BW + cx0;
#pragma unroll
            for (int j = 0; j < 6; j++) nn[r][j] = rp[j - 1];
        }
#pragma unroll
        for (int i = 0; i < 4; i++) {
            float T11 = nn[1][i+1] + nn[2][i+1] + nn[1][i+2] + nn[2][i+2];
            float T01 = nn[0][i+1] + nn[1][i+1] + nn[0][i+2] + nn[1][i+2];
            float T10 = nn[1][i]   + nn[2][i]   + nn[1][i+1] + nn[2][i+1];
            float T00 = nn[0][i]   + nn[1][i]   + nn[0][i+1] + nn[1][i+1];
            v1[i] = 1.0f / __fsqrt_rn(T11 + 1e-4f);
            v2[i] = 1.0f / __fsqrt_rn(T01 + 1e-4f);
            v3[i] = 1.0f / __fsqrt_rn(T10 + 1e-4f);
            v4[i] = 1.0f / __fsqrt_rn(T00 + 1e-4f);
        }
    }

    float h[4][18];
#pragma unroll
    for (int o = 0; o < 9; o++) {
        uint4 q = *(const uint4*)(hist + (((size_t)b * 9 + o) * BH + oy) * BW + cx0);
        unsigned vs[4] = {q.x, q.y, q.z, q.w};
#pragma unroll
        for (int i = 0; i < 4; i++) {
            float2 f = __half22float2(*(__half2*)&vs[i]);
            h[i][o] = f.x; h[i][o + 9] = f.y;
        }
    }

    bool msk[4];
#pragma unroll
    for (int i = 0; i < 4; i++) { int cxi = cx0 + i; msk[i] = (cxi >= 1 && cxi <= 126); }

    float t1[4] = {0,0,0,0}, t2[4] = {0,0,0,0}, t3[4] = {0,0,0,0}, t4[4] = {0,0,0,0};
    float* ob = out + ((size_t)b * 31) * BH * BW + (size_t)oy * BW + cx0;

#pragma unroll
    for (int o = 0; o < 18; o++) {
        float st[4];
#pragma unroll
        for (int i = 0; i < 4; i++) {
            float s = h[i][o];
            float a1 = fminf(s * v1[i], 0.2f);
            float a2 = fminf(s * v2[i], 0.2f);
            float a3 = fminf(s * v3[i], 0.2f);
            float a4 = fminf(s * v4[i], 0.2f);
            t1[i] += a1; t2[i] += a2; t3[i] += a3; t4[i] += a4;
            st[i] = msk[i] ? 0.5f * (a1 + a2 + a3 + a4) : 0.f;
        }
        *(float4*)(ob + (size_t)o * BH * BW) = make_float4(st[0], st[1], st[2], st[3]);
    }
#pragma unroll
    for (int o = 0; o < 9; o++) {
        float st[4];
#pragma unroll
        for (int i = 0; i < 4; i++) {
            float ss = h[i][o] + h[i][o + 9];
            float a1 = fminf(ss * v1[i], 0.2f);
            float a2 = fminf(ss * v2[i], 0.2f);
            float a3 = fminf(ss * v3[i], 0.2f);
            float a4 = fminf(ss * v4[i], 0.2f);
            st[i] = msk[i] ? 0.5f * (a1 + a2 + a3 + a4) : 0.f;
        }
        *(float4*)(ob + (size_t)(18 + o) * BH * BW) = make_float4(st[0], st[1], st[2], st[3]);
    }
    {
        float s1[4], s2[4], s3[4], s4[4];
#pragma unroll
        for (int i = 0; i < 4; i++) {
            s1[i] = msk[i] ? 0.2357f * t1[i] : 0.f;
            s2[i] = msk[i] ? 0.2357f * t2[i] : 0.f;
            s3[i] = msk[i] ? 0.2357f * t3[i] : 0.f;
            s4[i] = msk[i] ? 0.2357f * t4[i] : 0.f;
        }
        *(float4*)(ob + (size_t)27 * BH * BW) = make_float4(s1[0], s1[1], s1[2], s1[3]);
        *(float4*)(ob + (size_t)28 * BH * BW) = make_float4(s2[0], s2[1], s2[2], s2[3]);
        *(float4*)(ob + (size_t)29 * BH * BW) = make_float4(s3[0], s3[1], s3[2], s3[3]);
        *(float4*)(ob + (size_t)30 * BH * BW) = make_float4(s4[0], s4[1], s4[2], s4[3]);
    }
}

extern "C" void kernel_launch(void* const* d_in, const int* in_sizes, int n_in,
                              void* d_out, int out_size, void* d_ws, size_t ws_size,
                              hipStream_t stream)
{
    const float* img = (const float*)d_in[0];
    float* out = (float*)d_out;
    char* ws = (char*)d_ws;

    // workspace layout (256-aligned offsets):
    //   pk   : 16*510*512*4 = 16,711,680  @ 0
    //   hist : 16*9*128*128*4 = 9,437,184 @ 16,715,776  (half2-packed bins o|o+9)
    //   nrm  : 16*128*128*4 = 1,048,576  @ 26,152,960   (end 27,201,536)
    unsigned int* pk = (unsigned int*)ws;
    __half2* hist    = (__half2*)(ws + 16715776);
    float* nrm       = (float*)(ws + 26152960);

    dim3 b1(64, 4, 1), g1(2, 32, BATCH);
    hog_grad<<<g1, b1, 0, stream>>>(img, pk);

    dim3 b2(128, 2, 1), g2(1, BH / 2, BATCH);
    hog_hist<<<g2, b2, 0, stream>>>(pk, hist, nrm);

    dim3 b3(32, 8, 1), g3(1, BH / 8, BATCH);
    hog_feat<<<g3, b3, 0, stream>>>(hist, nrm, out);
}